// Round 2
// baseline (535.266 us; speedup 1.0000x reference)
//
#include <hip/hip_runtime.h>
#include <hip/hip_fp16.h>
#include <math.h>

#define NQ 14
#define NL 6
#define NT 512
#define BATCH 1024
#define NGATES (NL * NQ)
#define NK 16     // half2 regs per re/im = 32 amps/thread
#define NCOEF 20  // precomputed half2 coeffs (as f32-bit u32) per gate

// amp p = (tid<<5) | j, j=0..31. j bits 0-3 = reg k, j bit 4 = packing bit.
// storage bit map: 0-3 local k; 4 packing; 5-10 lane (tid bit p-5); 11-13 wave.
// Wire w <-> amp bit P = 13-w.
//
// R21: keep R20's layer structure (phase A rots on bits 0..10, S-perm,
// phase B local rots, F_l∘S inter-layer perm) but fix its two regressions:
//  (a) per-gate asm dependency fence (off depends on pr[0]) stops the
//      scheduler hoisting 11 gates' coefficient loads -> no VGPR spill.
//  (b) ring scatters had a rank-4 lane->bank map (4-way conflicts, the
//      constant 9.96M SQ_LDS_BANK_CONFLICT of R19/R20). Swizzle is now
//      sigma(a) = a ^ ((a>>5)&31) ^ G*(a>>10), G found per-perm by
//      compile-time GF(2) rank search so writes are 2-way (free); reads
//      are provably conflict-free for any G.

using H2 = __half2;

__device__ __forceinline__ unsigned h2u(H2 v){ return __builtin_bit_cast(unsigned, v); }
__device__ __forceinline__ H2 u2h(unsigned x){ return __builtin_bit_cast(H2, x); }
__device__ __forceinline__ float h2f(H2 v){ return __builtin_bit_cast(float, v); }
__device__ __forceinline__ H2 f2h(float x){ return __builtin_bit_cast(H2, x); }
__device__ __forceinline__ H2 shflx(H2 v, int m){
    return u2h((unsigned)__shfl_xor((int)h2u(v), m, 64));
}

// image of index v under layer-l CNOT ring (gate order w=0..13) — GF(2)-linear
__device__ constexpr int ring_F(int l, int v) {
    int r = (l % 13) + 1;
    for (int w = 0; w < NQ; ++w) {
        int pc = 13 - w, pt = 13 - ((w + r) % NQ);
        v ^= ((v >> pc) & 1) << pt;
    }
    return v;
}
// swap storage bits 11,12,13 <-> 0,1,2 (involution)
__device__ constexpr int swapS(int v) {
    return (v & 0x07F8) | ((v & 7) << 11) | ((v >> 11) & 7);
}
// perm applied after phase B: mode<0 -> S (mid-layer), else F_mode∘S (inter-layer)
__device__ constexpr int pmapf(int mode, int v) {
    int u = swapS(v);
    return (mode < 0) ? u : ring_F(mode, u);
}
// measurement sign mask: bit13(F5(S(s))) = parity(s & M13)
__device__ constexpr int calc_m13() {
    int m = 0;
    for (int v = 0; v < NQ; ++v)
        if ((ring_F(NL - 1, swapS(1 << v)) >> 13) & 1) m |= 1 << v;
    return m;
}

// ---- swizzle correction: sigma(a) = a ^ ((a>>5)&31) ^ gapply(G,(a>>10)&15)
// (modifies only bits 0-4 from bits >=5 -> always bijective; GF(2)-linear)
__device__ constexpr int gapply(int G, int h) {
    int r = 0;
    for (int i = 0; i < 4; ++i) if ((h >> i) & 1) r ^= (G >> (5 * i)) & 31;
    return r;
}
__device__ constexpr int bank_vec(int mode, int G, int i) {
    int a = pmapf(mode, 1 << (5 + i));   // image of lane bit i (linear, const-free)
    return (a ^ (a >> 5) ^ gapply(G, (a >> 10) & 15)) & 31;
}
__device__ constexpr int pm_rank(int mode, int G) {
    int basis[5] = {0, 0, 0, 0, 0};
    int r = 0;
    for (int i = 0; i < 6; ++i) {
        int x = bank_vec(mode, G, i);
        for (int b = 4; b >= 0; --b) {
            if (((x >> b) & 1) == 0) continue;
            if (basis[b]) { x ^= basis[b]; }
            else { basis[b] = x; ++r; break; }
        }
    }
    return r;   // rank of the lane->bank map; 5 => max 2 lanes/bank (free)
}
__device__ constexpr int find_g(int mode) {
    if (pm_rank(mode, 0) == 5) return 0;
    for (int col = 0; col < 4; ++col)
        for (int val = 1; val < 32; ++val) {
            int g = val << (5 * col);
            if (pm_rank(mode, g) == 5) return g;
        }
    for (int c1 = 0; c1 < 4; ++c1)
        for (int c2 = c1 + 1; c2 < 4; ++c2)
            for (int v1 = 1; v1 < 32; v1 <<= 1)
                for (int v2 = 1; v2 < 32; v2 <<= 1) {
                    int g = (v1 << (5 * c1)) | (v2 << (5 * c2));
                    if (pm_rank(mode, g) == 5) return g;
                }
    return 0;  // fallback: old behavior (correct, just conflicted)
}

// ---- prep: per-gate half2 coefficient table (batch-shared) into d_ws ----
// [0..7]=bc(m0..m7)  [8..11]=bc(-m1,-m3,-m5,-m7)
// [12]=(m0,m6) [13]=(m1,m7) [14]=(m2,m4) [15]=(m3,m5) [16]=(-m1,-m7) [17]=(-m3,-m5)
__global__ void prep_kernel(const float* __restrict__ wts, float* __restrict__ gm) {
    int g = blockIdx.x * blockDim.x + threadIdx.x;
    if (g < NGATES) {
        float phi = wts[g*3+0], th = wts[g*3+1], om = wts[g*3+2];
        float c = cosf(0.5f*th), s = sinf(0.5f*th);
        float a = 0.5f*(phi+om), bb = 0.5f*(phi-om);
        float ca = cosf(a), sa = sinf(a);
        float cb = cosf(bb), sb = sinf(bb);
        float m0 = c*ca, m1 = -c*sa;   // m00
        float m2 = -s*cb, m3 = -s*sb;  // m01
        float m4 = s*cb,  m5 = -s*sb;  // m10
        float m6 = c*ca,  m7 = c*sa;   // m11
        float* o = gm + g*NCOEF;
        o[0] = h2f(__float2half2_rn(m0)); o[1] = h2f(__float2half2_rn(m1));
        o[2] = h2f(__float2half2_rn(m2)); o[3] = h2f(__float2half2_rn(m3));
        o[4] = h2f(__float2half2_rn(m4)); o[5] = h2f(__float2half2_rn(m5));
        o[6] = h2f(__float2half2_rn(m6)); o[7] = h2f(__float2half2_rn(m7));
        o[8]  = h2f(__float2half2_rn(-m1));
        o[9]  = h2f(__float2half2_rn(-m3));
        o[10] = h2f(__float2half2_rn(-m5));
        o[11] = h2f(__float2half2_rn(-m7));
        o[12] = h2f(__floats2half2_rn(m0, m6));
        o[13] = h2f(__floats2half2_rn(m1, m7));
        o[14] = h2f(__floats2half2_rn(m2, m4));
        o[15] = h2f(__floats2half2_rn(m3, m5));
        o[16] = h2f(__floats2half2_rn(-m1, -m7));
        o[17] = h2f(__floats2half2_rn(-m3, -m5));
        o[18] = 0.f; o[19] = 0.f;
    }
}

// ---- Rot on storage bit P (P <= 10: never touches LDS) ----
template<int P>
__device__ __forceinline__ void rot_gate(H2 (&pr)[NK], H2 (&pi)[NK],
                                         const float* __restrict__ cw, int tid) {
    if constexpr (P < 4) {
        constexpr int M = 1 << P;
        H2 h0=f2h(cw[0]), h1=f2h(cw[1]), h2v=f2h(cw[2]), h3=f2h(cw[3]);
        H2 h4=f2h(cw[4]), h5=f2h(cw[5]), h6=f2h(cw[6]), h7=f2h(cw[7]);
        H2 nh1=f2h(cw[8]), nh3=f2h(cw[9]), nh5=f2h(cw[10]), nh7=f2h(cw[11]);
        #pragma unroll
        for (int i = 0; i < NK/2; ++i) {
            int k0 = ((i >> P) << (P+1)) | (i & (M-1));
            int k1 = k0 | M;
            H2 r0=pr[k0], i0=pi[k0], r1=pr[k1], i1=pi[k1];
            pr[k0] = __hfma2(h0,r0,__hfma2(nh1,i0,__hfma2(h2v,r1,__hmul2(nh3,i1))));
            pi[k0] = __hfma2(h0,i0,__hfma2(h1,r0,__hfma2(h2v,i1,__hmul2(h3,r1))));
            pr[k1] = __hfma2(h4,r0,__hfma2(nh5,i0,__hfma2(h6,r1,__hmul2(nh7,i1))));
            pi[k1] = __hfma2(h4,i0,__hfma2(h5,r0,__hfma2(h6,i1,__hmul2(h7,r1))));
        }
    } else if constexpr (P == 4) {
        // packing-bit rot: half-swap + per-half coeff H2s (all preloaded)
        H2 cAr=f2h(cw[12]), cAi=f2h(cw[13]), cBr=f2h(cw[14]), cBi=f2h(cw[15]);
        H2 nAi=f2h(cw[16]), nBi=f2h(cw[17]);
        #pragma unroll
        for (int k = 0; k < NK; ++k) {
            unsigned Ar = h2u(pr[k]), Ai = h2u(pi[k]);
            H2 sr = u2h((Ar>>16)|(Ar<<16)), si = u2h((Ai>>16)|(Ai<<16));
            H2 r = pr[k], i = pi[k];
            pr[k] = __hfma2(cAr,r,__hfma2(nAi,i,__hfma2(cBr,sr,__hmul2(nBi,si))));
            pi[k] = __hfma2(cAr,i,__hfma2(cAi,r,__hfma2(cBr,si,__hmul2(cBi,sr))));
        }
    } else {
        constexpr int LM = 1 << (P-5);
        int bit = (tid >> (P-5)) & 1;
        H2 a   = f2h(bit ? cw[6]  : cw[0]);
        H2 ai2 = f2h(bit ? cw[7]  : cw[1]);
        H2 nai = f2h(bit ? cw[11] : cw[8]);
        H2 b2  = f2h(bit ? cw[4]  : cw[2]);
        H2 bi2 = f2h(bit ? cw[5]  : cw[3]);
        H2 nbi = f2h(bit ? cw[10] : cw[9]);
        #pragma unroll
        for (int k = 0; k < NK; ++k) {
            H2 r = pr[k], i = pi[k];
            H2 qr = shflx(r, LM), qi = shflx(i, LM);
            pr[k] = __hfma2(a,r,__hfma2(nai,i,__hfma2(b2,qr,__hmul2(nbi,qi))));
            pi[k] = __hfma2(a,i,__hfma2(ai2,r,__hfma2(b2,qi,__hmul2(bi2,qr))));
        }
    }
}

// ---- gate wrapper with anti-hoist fence: the coefficient offset is made
// opaque AND data-dependent on the current state, so gate g+1's coefficient
// loads cannot be scheduled before gate g's math. Bounds live coeff regs to
// ~1 gate (R20 hoisted ~11 gates' worth -> 128 VGPR + 27 MB scratch spill).
template<int P>
__device__ __forceinline__ void rot_site(H2 (&pr)[NK], H2 (&pi)[NK],
                                         const float* __restrict__ gm, int gi, int tid) {
    int off = gi * NCOEF;
    asm volatile("" : "+s"(off) : "v"(h2u(pr[0])));
    rot_gate<P>(pr, pi, gm + off, tid);
}

// ---- one GF(2)-linear LDS permutation (scatter write, swizzled read) ----
// slot(a) = a ^ ((a>>5)&31) ^ gapply(G,(a>>10)&15); G chosen at compile time
// so the write-side lane->bank map has rank 5 (2-way max = free). Read side
// is rank-5 for any G.
template<int MODE>
__device__ __forceinline__ void perm_exchange(H2 (&pr)[NK], H2 (&pi)[NK],
                                              int tid, unsigned* ub) {
    constexpr int G = find_g(MODE);
    int base = pmapf(MODE, tid << 5);   // linear: M(p) = M(tid<<5) ^ M(j)
    int gbase = gapply(G, (base >> 10) & 15);
    #pragma unroll
    for (int k = 0; k < NK; ++k) {
        unsigned wlo = (h2u(pr[k]) & 0xFFFFu) | (h2u(pi[k]) << 16);      // amp j=k
        unsigned whi = (h2u(pr[k]) >> 16) | (h2u(pi[k]) & 0xFFFF0000u);  // amp j=k|16
        int flo = base ^ pmapf(MODE, k);        // pmapf/gapply of k fold to consts
        int fhi = base ^ pmapf(MODE, k | 16);
        int alo = flo ^ ((flo >> 5) & 31) ^ gbase ^ gapply(G, (pmapf(MODE, k) >> 10) & 15);
        int ahi = fhi ^ ((fhi >> 5) & 31) ^ gbase ^ gapply(G, (pmapf(MODE, k | 16) >> 10) & 15);
        ub[alo] = wlo;
        ub[ahi] = whi;
    }
    __syncthreads();
    int grd = (tid & 31) ^ gapply(G, (tid >> 5) & 15);   // read: sigma(tid<<5|j)
    #pragma unroll
    for (int k = 0; k < NK; ++k) {
        unsigned wlo = ub[((tid << 5) | k) ^ grd];
        unsigned whi = ub[((tid << 5) | (k | 16)) ^ grd];
        pr[k] = u2h((wlo & 0xFFFFu) | (whi << 16));
        pi[k] = u2h((wlo >> 16) | (whi & 0xFFFF0000u));
    }
    __syncthreads();
}

// ---- compile-time circuit drivers ----
template<int L, int P>
__device__ __forceinline__ void do_rotsA(H2 (&pr)[NK], H2 (&pi)[NK],
                                         const float* __restrict__ gm, int tid) {
    rot_site<P>(pr, pi, gm, L*NQ + (13-P), tid);   // wire 13-P at bit P
    if constexpr (P < 10) do_rotsA<L, P+1>(pr, pi, gm, tid);
}

template<int L>
__device__ __forceinline__ void do_layer(H2 (&pr)[NK], H2 (&pi)[NK],
                                         const float* __restrict__ gm, int tid,
                                         unsigned* ub) {
    do_rotsA<L, 0>(pr, pi, gm, tid);          // wires 13..3
    perm_exchange<-1>(pr, pi, tid, ub);       // S: bits 11-13 <-> 0-2
    rot_site<0>(pr, pi, gm, L*NQ + 2, tid);   // wire 2 now at bit 0
    rot_site<1>(pr, pi, gm, L*NQ + 1, tid);   // wire 1 at bit 1
    rot_site<2>(pr, pi, gm, L*NQ + 0, tid);   // wire 0 at bit 2
    if constexpr (L < NL-1) {
        perm_exchange<L>(pr, pi, tid, ub);    // F_L ∘ S: ring + back to canonical
        do_layer<L+1>(pr, pi, gm, tid, ub);
    }
    // last layer: ring folded into measurement sign
}

__global__ void __launch_bounds__(NT)
qsim_kernel(
    const float* __restrict__ x,
    const float* __restrict__ gm,
    float* __restrict__ out)
{
    __shared__ unsigned ub[NT * NK * 2];   // 64 KB -> 2 blocks/CU
    const int tid = threadIdx.x;
    const int b = blockIdx.x;
    const float* xb = x + b * NQ;

    // ---- direct product-state init (fp32 math, pack to fp16) ----
    H2 pr[NK], pi[NK];
    {
        float cr = 1.f, ci = 0.f;
        #pragma unroll
        for (int bb = 0; bb < 9; ++bb) {       // tid bit bb = amp bit 5+bb = wire 8-bb
            float s, c; __sincosf(0.5f * xb[8 - bb], &s, &c);
            if ((tid >> bb) & 1) { float nr = s*ci, ni = -s*cr; cr = nr; ci = ni; }
            else                 { cr *= c; ci *= c; }
        }
        float lc[4], ls[4];                     // k bit bb = wire 13-bb
        #pragma unroll
        for (int bb = 0; bb < 4; ++bb) __sincosf(0.5f * xb[13 - bb], &ls[bb], &lc[bb]);
        float s9, c9; __sincosf(0.5f * xb[9], &s9, &c9);   // packing bit = wire 9
        #pragma unroll
        for (int k = 0; k < NK; ++k) {
            float rr = cr, ii = ci;
            #pragma unroll
            for (int bb = 0; bb < 4; ++bb) {
                if ((k >> bb) & 1) { float nr = ls[bb]*ii, ni = -ls[bb]*rr; rr = nr; ii = ni; }
                else               { rr *= lc[bb]; ii *= lc[bb]; }
            }
            pr[k] = __floats2half2_rn(rr*c9,  s9*ii);
            pi[k] = __floats2half2_rn(ii*c9, -s9*rr);
        }
    }

    do_layer<0>(pr, pi, gm, tid, ub);

    // ---- <Z0>: state is in layout S; sign = bit13(F5(S(s))) = parity(s&M13) ----
    constexpr int M13 = calc_m13();
    int tpar = __builtin_popcount((tid << 5) & M13) & 1;
    float acc = 0.f;
    #pragma unroll
    for (int k = 0; k < NK; ++k) {
        float a=__low2float(pr[k]), c=__high2float(pr[k]);
        float d=__low2float(pi[k]), e=__high2float(pi[k]);
        float vlo = a*a + d*d, vhi = c*c + e*e;
        int slo = tpar ^ (__builtin_popcount(k & M13) & 1);          // folds per k
        int shi = tpar ^ (__builtin_popcount((k | 16) & M13) & 1);
        acc += slo ? -vlo : vlo;
        acc += shi ? -vhi : vhi;
    }
    #pragma unroll
    for (int off = 32; off > 0; off >>= 1) acc += __shfl_down(acc, off, 64);
    __syncthreads();
    float* f = (float*)ub;
    if ((tid & 63) == 0) f[tid >> 6] = acc;
    __syncthreads();
    if (tid == 0) {
        float s = 0.f;
        #pragma unroll
        for (int w = 0; w < NT/64; ++w) s += f[w];
        out[b] = s;
    }
}

extern "C" void kernel_launch(void* const* d_in, const int* in_sizes, int n_in,
                              void* d_out, int out_size, void* d_ws, size_t ws_size,
                              hipStream_t stream) {
    const float* x = (const float*)d_in[0];   // (1024, 14) float32
    const float* w = (const float*)d_in[1];   // (6, 14, 3) float32
    float* out = (float*)d_out;               // (1024,) float32
    float* gm = (float*)d_ws;                 // 84*20 floats of packed coeffs

    prep_kernel<<<1, 128, 0, stream>>>(w, gm);
    qsim_kernel<<<BATCH, NT, 0, stream>>>(x, gm, out);
}

// Round 3
// 343.933 us; speedup vs baseline: 1.5563x; 1.5563x over previous
//
#include <hip/hip_runtime.h>
#include <hip/hip_fp16.h>
#include <math.h>

#define NQ 14
#define NL 6
#define NT 512
#define BATCH 1024
#define NGATES (NL * NQ)
#define NK 16    // half2 regs per re/im = 32 amps/thread
#define NCOEF 8  // 8 float matrix entries per gate (SGPR-friendly; convert at use)

// amp p = (tid<<5) | j, j=0..31. j bits 0-3 = reg k, j bit 4 = packing bit.
// storage bit map: 0-3 local k; 4 packing; 5-10 lane (tid bit p-5); 11-13 wave.
// Wire w <-> amp bit P = 13-w.
//
// R22: R20's layer structure + R19's coefficient format.
//  - Layer: phase A rots on storage bits 0..10 (register/shuffle only),
//    S-perm (bits 11-13 <-> 0-2), phase B local rots, F_l∘S inter-layer perm.
//    Last ring folded into the measurement sign mask.
//  - Coeffs stay 8 raw floats/gate: hoisted s_loads park in SGPRs; bc()
//    converts to VGPR half2 at use. (R20's pre-packed H2 table forced early
//    SGPR->VGPR copies -> 128 VGPR + scratch spill. R21's anti-hoist fence
//    serialized load->math chains -> 535us. Both reverted.)
//  - Perm barriers: entry + mid only; no trailing barrier, so phase math
//    starts as soon as this wave's reads return.

using H2 = __half2;

__device__ __forceinline__ unsigned h2u(H2 v){ return __builtin_bit_cast(unsigned, v); }
__device__ __forceinline__ H2 u2h(unsigned x){ return __builtin_bit_cast(H2, x); }
__device__ __forceinline__ H2 bc(float x){ return __float2half2_rn(x); }
__device__ __forceinline__ H2 shflx(H2 v, int m){
    return u2h((unsigned)__shfl_xor((int)h2u(v), m, 64));
}

// image of index v under layer-l CNOT ring (gate order w=0..13) — GF(2)-linear
__device__ constexpr int ring_F(int l, int v) {
    int r = (l % 13) + 1;
    for (int w = 0; w < NQ; ++w) {
        int pc = 13 - w, pt = 13 - ((w + r) % NQ);
        v ^= ((v >> pc) & 1) << pt;
    }
    return v;
}
// swap storage bits 11,12,13 <-> 0,1,2 (involution)
__device__ constexpr int swapS(int v) {
    return (v & 0x07F8) | ((v & 7) << 11) | ((v >> 11) & 7);
}
// perm applied after phase B: mode<0 -> S (mid-layer), else F_mode∘S (inter-layer)
__device__ constexpr int pmapf(int mode, int v) {
    int u = swapS(v);
    return (mode < 0) ? u : ring_F(mode, u);
}
// measurement sign mask: bit13(F5(S(s))) = parity(s & M13)
__device__ constexpr int calc_m13() {
    int m = 0;
    for (int v = 0; v < NQ; ++v)
        if ((ring_F(NL - 1, swapS(1 << v)) >> 13) & 1) m |= 1 << v;
    return m;
}

// ---- swizzle correction: slot(a) = a ^ ((a>>5)&31) ^ gapply(G,(a>>10)&15)
// (modifies only bits 0-4 from bits >=5 -> always bijective; GF(2)-linear)
__device__ constexpr int gapply(int G, int h) {
    int r = 0;
    for (int i = 0; i < 4; ++i) if ((h >> i) & 1) r ^= (G >> (5 * i)) & 31;
    return r;
}
__device__ constexpr int bank_vec(int mode, int G, int i) {
    int a = pmapf(mode, 1 << (5 + i));   // image of lane bit i (linear)
    return (a ^ (a >> 5) ^ gapply(G, (a >> 10) & 15)) & 31;
}
__device__ constexpr int pm_rank(int mode, int G) {
    int basis[5] = {0, 0, 0, 0, 0};
    int r = 0;
    for (int i = 0; i < 6; ++i) {
        int x = bank_vec(mode, G, i);
        for (int b = 4; b >= 0; --b) {
            if (((x >> b) & 1) == 0) continue;
            if (basis[b]) { x ^= basis[b]; }
            else { basis[b] = x; ++r; break; }
        }
    }
    return r;   // 5 => max 2 lanes/bank on the write scatter (free)
}
__device__ constexpr int find_g(int mode) {
    if (pm_rank(mode, 0) == 5) return 0;
    for (int col = 0; col < 4; ++col)
        for (int val = 1; val < 32; ++val) {
            int g = val << (5 * col);
            if (pm_rank(mode, g) == 5) return g;
        }
    for (int c1 = 0; c1 < 4; ++c1)
        for (int c2 = c1 + 1; c2 < 4; ++c2)
            for (int v1 = 1; v1 < 32; v1 <<= 1)
                for (int v2 = 1; v2 < 32; v2 <<= 1) {
                    int g = (v1 << (5 * c1)) | (v2 << (5 * c2));
                    if (pm_rank(mode, g) == 5) return g;
                }
    return 0;  // fallback: unswizzled-correction behavior (correct)
}

// ---- prep: Rot matrices (batch-shared, 8 floats/gate) into d_ws ----
__global__ void prep_kernel(const float* __restrict__ wts, float* __restrict__ gm) {
    int g = blockIdx.x * blockDim.x + threadIdx.x;
    if (g < NGATES) {
        float phi = wts[g*3+0], th = wts[g*3+1], om = wts[g*3+2];
        float c = cosf(0.5f*th), s = sinf(0.5f*th);
        float a = 0.5f*(phi+om), bb = 0.5f*(phi-om);
        float ca = cosf(a), sa = sinf(a);
        float cb = cosf(bb), sb = sinf(bb);
        gm[g*8+0] = c*ca;  gm[g*8+1] = -c*sa;   // m00
        gm[g*8+2] = -s*cb; gm[g*8+3] = -s*sb;   // m01
        gm[g*8+4] = s*cb;  gm[g*8+5] = -s*sb;   // m10
        gm[g*8+6] = c*ca;  gm[g*8+7] = c*sa;    // m11
    }
}

// ---- Rot on storage bit P (P <= 10: never touches LDS) ----
template<int P>
__device__ __forceinline__ void rot_gate(H2 (&pr)[NK], H2 (&pi)[NK],
                                         const float* __restrict__ m, int tid) {
    float m0=m[0],m1=m[1],m2=m[2],m3=m[3],m4=m[4],m5=m[5],m6=m[6],m7=m[7];
    if constexpr (P < 4) {
        constexpr int M = 1 << P;
        H2 h0=bc(m0),h1=bc(m1),nh1=bc(-m1),h2v=bc(m2),h3=bc(m3),nh3=bc(-m3);
        H2 h4=bc(m4),h5=bc(m5),nh5=bc(-m5),h6=bc(m6),h7=bc(m7),nh7=bc(-m7);
        #pragma unroll
        for (int i = 0; i < NK/2; ++i) {
            int k0 = ((i >> P) << (P+1)) | (i & (M-1));
            int k1 = k0 | M;
            H2 r0=pr[k0], i0=pi[k0], r1=pr[k1], i1=pi[k1];
            pr[k0] = __hfma2(h0,r0,__hfma2(nh1,i0,__hfma2(h2v,r1,__hmul2(nh3,i1))));
            pi[k0] = __hfma2(h0,i0,__hfma2(h1,r0,__hfma2(h2v,i1,__hmul2(h3,r1))));
            pr[k1] = __hfma2(h4,r0,__hfma2(nh5,i0,__hfma2(h6,r1,__hmul2(nh7,i1))));
            pi[k1] = __hfma2(h4,i0,__hfma2(h5,r0,__hfma2(h6,i1,__hmul2(h7,r1))));
        }
    } else if constexpr (P == 4) {
        // packing-bit rot: half-swap + per-half coeff H2s
        H2 cAr = __floats2half2_rn(m0, m6), cAi = __floats2half2_rn(m1, m7);
        H2 nAi = __floats2half2_rn(-m1,-m7);
        H2 cBr = __floats2half2_rn(m2, m4), cBi = __floats2half2_rn(m3, m5);
        H2 nBi = __floats2half2_rn(-m3,-m5);
        #pragma unroll
        for (int k = 0; k < NK; ++k) {
            unsigned Ar = h2u(pr[k]), Ai = h2u(pi[k]);
            H2 sr = u2h((Ar>>16)|(Ar<<16)), si = u2h((Ai>>16)|(Ai<<16));
            H2 r = pr[k], i = pi[k];
            pr[k] = __hfma2(cAr,r,__hfma2(nAi,i,__hfma2(cBr,sr,__hmul2(nBi,si))));
            pi[k] = __hfma2(cAr,i,__hfma2(cAi,r,__hfma2(cBr,si,__hmul2(cBi,sr))));
        }
    } else {
        constexpr int LM = 1 << (P-5);
        int bit = (tid >> (P-5)) & 1;
        float cAr = bit ? m6 : m0, cAi = bit ? m7 : m1;
        float cBr = bit ? m4 : m2, cBi = bit ? m5 : m3;
        H2 a=bc(cAr), ai2=bc(cAi), nai=bc(-cAi), b2=bc(cBr), bi2=bc(cBi), nbi=bc(-cBi);
        #pragma unroll
        for (int k = 0; k < NK; ++k) {
            H2 r = pr[k], i = pi[k];
            H2 qr = shflx(r, LM), qi = shflx(i, LM);
            pr[k] = __hfma2(a,r,__hfma2(nai,i,__hfma2(b2,qr,__hmul2(nbi,qi))));
            pi[k] = __hfma2(a,i,__hfma2(ai2,r,__hfma2(b2,qi,__hmul2(bi2,qr))));
        }
    }
}

// ---- one GF(2)-linear LDS permutation (scatter write, swizzled read) ----
// slot(a) = a ^ ((a>>5)&31) ^ gapply(G,(a>>10)&15); G chosen at compile time
// so the write-side lane->bank map has rank 5 (2-way max = free). Read side
// is 2-way for any G. Barriers: entry (prior perm's reads done) + mid; no
// trailing barrier -> following math overlaps other waves' reads.
template<int MODE>
__device__ __forceinline__ void perm_exchange(H2 (&pr)[NK], H2 (&pi)[NK],
                                              int tid, unsigned* ub) {
    constexpr int G = find_g(MODE);
    int base = pmapf(MODE, tid << 5);   // linear: M(p) = M(tid<<5) ^ M(j)
    int gbase = gapply(G, (base >> 10) & 15);
    __syncthreads();
    #pragma unroll
    for (int k = 0; k < NK; ++k) {
        unsigned wlo = (h2u(pr[k]) & 0xFFFFu) | (h2u(pi[k]) << 16);      // amp j=k
        unsigned whi = (h2u(pr[k]) >> 16) | (h2u(pi[k]) & 0xFFFF0000u);  // amp j=k|16
        int flo = base ^ pmapf(MODE, k);        // pmapf/gapply of k fold to consts
        int fhi = base ^ pmapf(MODE, k | 16);
        int alo = flo ^ ((flo >> 5) & 31) ^ gbase ^ gapply(G, (pmapf(MODE, k) >> 10) & 15);
        int ahi = fhi ^ ((fhi >> 5) & 31) ^ gbase ^ gapply(G, (pmapf(MODE, k | 16) >> 10) & 15);
        ub[alo] = wlo;
        ub[ahi] = whi;
    }
    __syncthreads();
    int grd = (tid & 31) ^ gapply(G, (tid >> 5) & 15);   // read: slot(tid<<5|j)
    #pragma unroll
    for (int k = 0; k < NK; ++k) {
        unsigned wlo = ub[((tid << 5) | k) ^ grd];
        unsigned whi = ub[((tid << 5) | (k | 16)) ^ grd];
        pr[k] = u2h((wlo & 0xFFFFu) | (whi << 16));
        pi[k] = u2h((wlo >> 16) | (whi & 0xFFFF0000u));
    }
}

// ---- compile-time circuit drivers ----
template<int L, int P>
__device__ __forceinline__ void do_rotsA(H2 (&pr)[NK], H2 (&pi)[NK],
                                         const float* __restrict__ gm, int tid) {
    rot_gate<P>(pr, pi, gm + (L*NQ + (13-P))*NCOEF, tid);   // wire 13-P at bit P
    if constexpr (P < 10) do_rotsA<L, P+1>(pr, pi, gm, tid);
}

template<int L>
__device__ __forceinline__ void do_layer(H2 (&pr)[NK], H2 (&pi)[NK],
                                         const float* __restrict__ gm, int tid,
                                         unsigned* ub) {
    do_rotsA<L, 0>(pr, pi, gm, tid);          // wires 13..3
    perm_exchange<-1>(pr, pi, tid, ub);       // S: bits 11-13 <-> 0-2
    rot_gate<0>(pr, pi, gm + (L*NQ + 2)*NCOEF, tid);  // wire 2 now at bit 0
    rot_gate<1>(pr, pi, gm + (L*NQ + 1)*NCOEF, tid);  // wire 1 at bit 1
    rot_gate<2>(pr, pi, gm + (L*NQ + 0)*NCOEF, tid);  // wire 0 at bit 2
    if constexpr (L < NL-1) {
        perm_exchange<L>(pr, pi, tid, ub);    // F_L ∘ S: ring + back to canonical
        do_layer<L+1>(pr, pi, gm, tid, ub);
    }
    // last layer: ring folded into measurement sign
}

__global__ void __launch_bounds__(NT)
qsim_kernel(
    const float* __restrict__ x,
    const float* __restrict__ gm,
    float* __restrict__ out)
{
    __shared__ unsigned ub[NT * NK * 2];   // 64 KB -> 2 blocks/CU
    const int tid = threadIdx.x;
    const int b = blockIdx.x;
    const float* xb = x + b * NQ;

    // ---- direct product-state init (fp32 math, pack to fp16) ----
    H2 pr[NK], pi[NK];
    {
        float cr = 1.f, ci = 0.f;
        #pragma unroll
        for (int bb = 0; bb < 9; ++bb) {       // tid bit bb = amp bit 5+bb = wire 8-bb
            float s, c; __sincosf(0.5f * xb[8 - bb], &s, &c);
            if ((tid >> bb) & 1) { float nr = s*ci, ni = -s*cr; cr = nr; ci = ni; }
            else                 { cr *= c; ci *= c; }
        }
        float lc[4], ls[4];                     // k bit bb = wire 13-bb
        #pragma unroll
        for (int bb = 0; bb < 4; ++bb) __sincosf(0.5f * xb[13 - bb], &ls[bb], &lc[bb]);
        float s9, c9; __sincosf(0.5f * xb[9], &s9, &c9);   // packing bit = wire 9
        #pragma unroll
        for (int k = 0; k < NK; ++k) {
            float rr = cr, ii = ci;
            #pragma unroll
            for (int bb = 0; bb < 4; ++bb) {
                if ((k >> bb) & 1) { float nr = ls[bb]*ii, ni = -ls[bb]*rr; rr = nr; ii = ni; }
                else               { rr *= lc[bb]; ii *= lc[bb]; }
            }
            pr[k] = __floats2half2_rn(rr*c9,  s9*ii);
            pi[k] = __floats2half2_rn(ii*c9, -s9*rr);
        }
    }

    do_layer<0>(pr, pi, gm, tid, ub);

    // ---- <Z0>: state is in layout S; sign = bit13(F5(S(s))) = parity(s&M13) ----
    constexpr int M13 = calc_m13();
    int tpar = __builtin_popcount((tid << 5) & M13) & 1;
    float acc = 0.f;
    #pragma unroll
    for (int k = 0; k < NK; ++k) {
        float a=__low2float(pr[k]), c=__high2float(pr[k]);
        float d=__low2float(pi[k]), e=__high2float(pi[k]);
        float vlo = a*a + d*d, vhi = c*c + e*e;
        int slo = tpar ^ (__builtin_popcount(k & M13) & 1);          // folds per k
        int shi = tpar ^ (__builtin_popcount((k | 16) & M13) & 1);
        acc += slo ? -vlo : vlo;
        acc += shi ? -vhi : vhi;
    }
    #pragma unroll
    for (int off = 32; off > 0; off >>= 1) acc += __shfl_down(acc, off, 64);
    __syncthreads();   // all waves' perm reads done before ub reuse
    float* f = (float*)ub;
    if ((tid & 63) == 0) f[tid >> 6] = acc;
    __syncthreads();
    if (tid == 0) {
        float s = 0.f;
        #pragma unroll
        for (int w = 0; w < NT/64; ++w) s += f[w];
        out[b] = s;
    }
}

extern "C" void kernel_launch(void* const* d_in, const int* in_sizes, int n_in,
                              void* d_out, int out_size, void* d_ws, size_t ws_size,
                              hipStream_t stream) {
    const float* x = (const float*)d_in[0];   // (1024, 14) float32
    const float* w = (const float*)d_in[1];   // (6, 14, 3) float32
    float* out = (float*)d_out;               // (1024,) float32
    float* gm = (float*)d_ws;                 // 84*8 floats of Rot matrices

    prep_kernel<<<1, 128, 0, stream>>>(w, gm);
    qsim_kernel<<<BATCH, NT, 0, stream>>>(x, gm, out);
}

// Round 4
// 302.917 us; speedup vs baseline: 1.7670x; 1.1354x over previous
//
#include <hip/hip_runtime.h>
#include <hip/hip_fp16.h>
#include <math.h>

#define NQ 14
#define NL 6
#define NT 512
#define BATCH 1024
#define NGATES (NL * NQ)
#define NK 16    // half2 regs per re/im = 32 amps/thread
#define NCOEF 8  // 8 float matrix entries per gate (SGPR-friendly; convert at use)

// amp p = (tid<<5) | j, j=0..31. j bits 0-3 = reg k, j bit 4 = packing bit.
// storage bit map: 0-3 local k; 4 packing; 5-10 lane (tid bit p-5); 11-13 wave.
// Wire w <-> amp bit P = 13-w.
//
// R23: R22 structure + register-pressure fixes to get back under the 64-VGPR
// occupancy step (R22: 84 VGPR -> occupancy 23% vs R19's 60 VGPR/40%).
//  (a) opaque-tid inside perm_exchange: the 6 perms' GF(2) address nets are
//      pure functions of tid; without this the compiler CSE-hoists all of
//      them to kernel entry (~15 regs live whole-kernel). Recompute is ~50
//      VALU ops per perm — noise.
//  (b) negated coeffs via __hneg2 at use: folds into v_pk_fma neg modifiers
//      (zero-cost), -4 live H2 per gate.
//  (c) __launch_bounds__(NT, 8) pins the allocator at <=64 VGPR.

using H2 = __half2;

__device__ __forceinline__ unsigned h2u(H2 v){ return __builtin_bit_cast(unsigned, v); }
__device__ __forceinline__ H2 u2h(unsigned x){ return __builtin_bit_cast(H2, x); }
__device__ __forceinline__ H2 bc(float x){ return __float2half2_rn(x); }
__device__ __forceinline__ H2 shflx(H2 v, int m){
    return u2h((unsigned)__shfl_xor((int)h2u(v), m, 64));
}

// image of index v under layer-l CNOT ring (gate order w=0..13) — GF(2)-linear
__device__ constexpr int ring_F(int l, int v) {
    int r = (l % 13) + 1;
    for (int w = 0; w < NQ; ++w) {
        int pc = 13 - w, pt = 13 - ((w + r) % NQ);
        v ^= ((v >> pc) & 1) << pt;
    }
    return v;
}
// swap storage bits 11,12,13 <-> 0,1,2 (involution)
__device__ constexpr int swapS(int v) {
    return (v & 0x07F8) | ((v & 7) << 11) | ((v >> 11) & 7);
}
// perm applied after phase B: mode<0 -> S (mid-layer), else F_mode∘S (inter-layer)
__device__ constexpr int pmapf(int mode, int v) {
    int u = swapS(v);
    return (mode < 0) ? u : ring_F(mode, u);
}
// measurement sign mask: bit13(F5(S(s))) = parity(s & M13)
__device__ constexpr int calc_m13() {
    int m = 0;
    for (int v = 0; v < NQ; ++v)
        if ((ring_F(NL - 1, swapS(1 << v)) >> 13) & 1) m |= 1 << v;
    return m;
}

// ---- swizzle correction: slot(a) = a ^ ((a>>5)&31) ^ gapply(G,(a>>10)&15)
// (modifies only bits 0-4 from bits >=5 -> always bijective; GF(2)-linear)
__device__ constexpr int gapply(int G, int h) {
    int r = 0;
    for (int i = 0; i < 4; ++i) if ((h >> i) & 1) r ^= (G >> (5 * i)) & 31;
    return r;
}
__device__ constexpr int bank_vec(int mode, int G, int i) {
    int a = pmapf(mode, 1 << (5 + i));   // image of lane bit i (linear)
    return (a ^ (a >> 5) ^ gapply(G, (a >> 10) & 15)) & 31;
}
__device__ constexpr int pm_rank(int mode, int G) {
    int basis[5] = {0, 0, 0, 0, 0};
    int r = 0;
    for (int i = 0; i < 6; ++i) {
        int x = bank_vec(mode, G, i);
        for (int b = 4; b >= 0; --b) {
            if (((x >> b) & 1) == 0) continue;
            if (basis[b]) { x ^= basis[b]; }
            else { basis[b] = x; ++r; break; }
        }
    }
    return r;   // 5 => max 2 lanes/bank on the write scatter (free)
}
__device__ constexpr int find_g(int mode) {
    if (pm_rank(mode, 0) == 5) return 0;
    for (int col = 0; col < 4; ++col)
        for (int val = 1; val < 32; ++val) {
            int g = val << (5 * col);
            if (pm_rank(mode, g) == 5) return g;
        }
    for (int c1 = 0; c1 < 4; ++c1)
        for (int c2 = c1 + 1; c2 < 4; ++c2)
            for (int v1 = 1; v1 < 32; v1 <<= 1)
                for (int v2 = 1; v2 < 32; v2 <<= 1) {
                    int g = (v1 << (5 * c1)) | (v2 << (5 * c2));
                    if (pm_rank(mode, g) == 5) return g;
                }
    return 0;  // fallback: unswizzled-correction behavior (correct)
}

// ---- prep: Rot matrices (batch-shared, 8 floats/gate) into d_ws ----
__global__ void prep_kernel(const float* __restrict__ wts, float* __restrict__ gm) {
    int g = blockIdx.x * blockDim.x + threadIdx.x;
    if (g < NGATES) {
        float phi = wts[g*3+0], th = wts[g*3+1], om = wts[g*3+2];
        float c = cosf(0.5f*th), s = sinf(0.5f*th);
        float a = 0.5f*(phi+om), bb = 0.5f*(phi-om);
        float ca = cosf(a), sa = sinf(a);
        float cb = cosf(bb), sb = sinf(bb);
        gm[g*8+0] = c*ca;  gm[g*8+1] = -c*sa;   // m00
        gm[g*8+2] = -s*cb; gm[g*8+3] = -s*sb;   // m01
        gm[g*8+4] = s*cb;  gm[g*8+5] = -s*sb;   // m10
        gm[g*8+6] = c*ca;  gm[g*8+7] = c*sa;    // m11
    }
}

// ---- Rot on storage bit P (P <= 10: never touches LDS) ----
// Negated coefficients are expressed as __hneg2 at use: LLVM folds the fneg
// into v_pk_fma_f16 neg_lo/neg_hi modifiers -> no extra ops, no extra regs.
template<int P>
__device__ __forceinline__ void rot_gate(H2 (&pr)[NK], H2 (&pi)[NK],
                                         const float* __restrict__ m, int tid) {
    float m0=m[0],m1=m[1],m2=m[2],m3=m[3],m4=m[4],m5=m[5],m6=m[6],m7=m[7];
    if constexpr (P < 4) {
        constexpr int M = 1 << P;
        H2 h0=bc(m0),h1=bc(m1),h2v=bc(m2),h3=bc(m3);
        H2 h4=bc(m4),h5=bc(m5),h6=bc(m6),h7=bc(m7);
        #pragma unroll
        for (int i = 0; i < NK/2; ++i) {
            int k0 = ((i >> P) << (P+1)) | (i & (M-1));
            int k1 = k0 | M;
            H2 r0=pr[k0], i0=pi[k0], r1=pr[k1], i1=pi[k1];
            pr[k0] = __hfma2(h0,r0,__hfma2(__hneg2(h1),i0,__hfma2(h2v,r1,__hmul2(__hneg2(h3),i1))));
            pi[k0] = __hfma2(h0,i0,__hfma2(h1,r0,__hfma2(h2v,i1,__hmul2(h3,r1))));
            pr[k1] = __hfma2(h4,r0,__hfma2(__hneg2(h5),i0,__hfma2(h6,r1,__hmul2(__hneg2(h7),i1))));
            pi[k1] = __hfma2(h4,i0,__hfma2(h5,r0,__hfma2(h6,i1,__hmul2(h7,r1))));
        }
    } else if constexpr (P == 4) {
        // packing-bit rot: half-swap + per-half coeff H2s
        H2 cAr = __floats2half2_rn(m0, m6), cAi = __floats2half2_rn(m1, m7);
        H2 cBr = __floats2half2_rn(m2, m4), cBi = __floats2half2_rn(m3, m5);
        #pragma unroll
        for (int k = 0; k < NK; ++k) {
            unsigned Ar = h2u(pr[k]), Ai = h2u(pi[k]);
            H2 sr = u2h((Ar>>16)|(Ar<<16)), si = u2h((Ai>>16)|(Ai<<16));
            H2 r = pr[k], i = pi[k];
            pr[k] = __hfma2(cAr,r,__hfma2(__hneg2(cAi),i,__hfma2(cBr,sr,__hmul2(__hneg2(cBi),si))));
            pi[k] = __hfma2(cAr,i,__hfma2(cAi,r,__hfma2(cBr,si,__hmul2(cBi,sr))));
        }
    } else {
        constexpr int LM = 1 << (P-5);
        int bit = (tid >> (P-5)) & 1;
        float cAr = bit ? m6 : m0, cAi = bit ? m7 : m1;
        float cBr = bit ? m4 : m2, cBi = bit ? m5 : m3;
        H2 a=bc(cAr), ai2=bc(cAi), b2=bc(cBr), bi2=bc(cBi);
        #pragma unroll
        for (int k = 0; k < NK; ++k) {
            H2 r = pr[k], i = pi[k];
            H2 qr = shflx(r, LM), qi = shflx(i, LM);
            pr[k] = __hfma2(a,r,__hfma2(__hneg2(ai2),i,__hfma2(b2,qr,__hmul2(__hneg2(bi2),qi))));
            pi[k] = __hfma2(a,i,__hfma2(ai2,r,__hfma2(b2,qi,__hmul2(bi2,qr))));
        }
    }
}

// ---- one GF(2)-linear LDS permutation (scatter write, swizzled read) ----
// slot(a) = a ^ ((a>>5)&31) ^ gapply(G,(a>>10)&15); G chosen at compile time
// so the write-side lane->bank map has rank 5 (2-way max = free). Read side
// is 2-way for any G. Barriers: entry (prior perm's reads done) + mid; no
// trailing barrier -> following math overlaps other waves' reads.
// Opaque-tid: address net depends on an asm-laundered copy of tid so the 6
// perms' nets can't be CSE-hoisted to kernel entry (R22: +~15 VGPR).
template<int MODE>
__device__ __forceinline__ void perm_exchange(H2 (&pr)[NK], H2 (&pi)[NK],
                                              int tid, unsigned* ub) {
    constexpr int G = find_g(MODE);
    int t = tid;
    asm volatile("" : "+v"(t));
    int base = pmapf(MODE, t << 5);   // linear: M(p) = M(tid<<5) ^ M(j)
    int gbase = gapply(G, (base >> 10) & 15);
    __syncthreads();
    #pragma unroll
    for (int k = 0; k < NK; ++k) {
        unsigned wlo = (h2u(pr[k]) & 0xFFFFu) | (h2u(pi[k]) << 16);      // amp j=k
        unsigned whi = (h2u(pr[k]) >> 16) | (h2u(pi[k]) & 0xFFFF0000u);  // amp j=k|16
        int flo = base ^ pmapf(MODE, k);        // pmapf/gapply of k fold to consts
        int fhi = base ^ pmapf(MODE, k | 16);
        int alo = flo ^ ((flo >> 5) & 31) ^ gbase ^ gapply(G, (pmapf(MODE, k) >> 10) & 15);
        int ahi = fhi ^ ((fhi >> 5) & 31) ^ gbase ^ gapply(G, (pmapf(MODE, k | 16) >> 10) & 15);
        ub[alo] = wlo;
        ub[ahi] = whi;
    }
    __syncthreads();
    int grd = (t & 31) ^ gapply(G, (t >> 5) & 15);   // read: slot(tid<<5|j)
    #pragma unroll
    for (int k = 0; k < NK; ++k) {
        unsigned wlo = ub[((t << 5) | k) ^ grd];
        unsigned whi = ub[((t << 5) | (k | 16)) ^ grd];
        pr[k] = u2h((wlo & 0xFFFFu) | (whi << 16));
        pi[k] = u2h((wlo >> 16) | (whi & 0xFFFF0000u));
    }
}

// ---- compile-time circuit drivers ----
template<int L, int P>
__device__ __forceinline__ void do_rotsA(H2 (&pr)[NK], H2 (&pi)[NK],
                                         const float* __restrict__ gm, int tid) {
    rot_gate<P>(pr, pi, gm + (L*NQ + (13-P))*NCOEF, tid);   // wire 13-P at bit P
    if constexpr (P < 10) do_rotsA<L, P+1>(pr, pi, gm, tid);
}

template<int L>
__device__ __forceinline__ void do_layer(H2 (&pr)[NK], H2 (&pi)[NK],
                                         const float* __restrict__ gm, int tid,
                                         unsigned* ub) {
    do_rotsA<L, 0>(pr, pi, gm, tid);          // wires 13..3
    perm_exchange<-1>(pr, pi, tid, ub);       // S: bits 11-13 <-> 0-2
    rot_gate<0>(pr, pi, gm + (L*NQ + 2)*NCOEF, tid);  // wire 2 now at bit 0
    rot_gate<1>(pr, pi, gm + (L*NQ + 1)*NCOEF, tid);  // wire 1 at bit 1
    rot_gate<2>(pr, pi, gm + (L*NQ + 0)*NCOEF, tid);  // wire 0 at bit 2
    if constexpr (L < NL-1) {
        perm_exchange<L>(pr, pi, tid, ub);    // F_L ∘ S: ring + back to canonical
        do_layer<L+1>(pr, pi, gm, tid, ub);
    }
    // last layer: ring folded into measurement sign
}

__global__ void __launch_bounds__(NT, 8)
qsim_kernel(
    const float* __restrict__ x,
    const float* __restrict__ gm,
    float* __restrict__ out)
{
    __shared__ unsigned ub[NT * NK * 2];   // 64 KB -> 2 blocks/CU
    const int tid = threadIdx.x;
    const int b = blockIdx.x;
    const float* xb = x + b * NQ;

    // ---- direct product-state init (fp32 math, pack to fp16) ----
    H2 pr[NK], pi[NK];
    {
        float cr = 1.f, ci = 0.f;
        #pragma unroll
        for (int bb = 0; bb < 9; ++bb) {       // tid bit bb = amp bit 5+bb = wire 8-bb
            float s, c; __sincosf(0.5f * xb[8 - bb], &s, &c);
            if ((tid >> bb) & 1) { float nr = s*ci, ni = -s*cr; cr = nr; ci = ni; }
            else                 { cr *= c; ci *= c; }
        }
        float lc[4], ls[4];                     // k bit bb = wire 13-bb
        #pragma unroll
        for (int bb = 0; bb < 4; ++bb) __sincosf(0.5f * xb[13 - bb], &ls[bb], &lc[bb]);
        float s9, c9; __sincosf(0.5f * xb[9], &s9, &c9);   // packing bit = wire 9
        #pragma unroll
        for (int k = 0; k < NK; ++k) {
            float rr = cr, ii = ci;
            #pragma unroll
            for (int bb = 0; bb < 4; ++bb) {
                if ((k >> bb) & 1) { float nr = ls[bb]*ii, ni = -ls[bb]*rr; rr = nr; ii = ni; }
                else               { rr *= lc[bb]; ii *= lc[bb]; }
            }
            pr[k] = __floats2half2_rn(rr*c9,  s9*ii);
            pi[k] = __floats2half2_rn(ii*c9, -s9*rr);
        }
    }

    do_layer<0>(pr, pi, gm, tid, ub);

    // ---- <Z0>: state is in layout S; sign = bit13(F5(S(s))) = parity(s&M13) ----
    constexpr int M13 = calc_m13();
    int tpar = __builtin_popcount((tid << 5) & M13) & 1;
    float acc = 0.f;
    #pragma unroll
    for (int k = 0; k < NK; ++k) {
        float a=__low2float(pr[k]), c=__high2float(pr[k]);
        float d=__low2float(pi[k]), e=__high2float(pi[k]);
        float vlo = a*a + d*d, vhi = c*c + e*e;
        int slo = tpar ^ (__builtin_popcount(k & M13) & 1);          // folds per k
        int shi = tpar ^ (__builtin_popcount((k | 16) & M13) & 1);
        acc += slo ? -vlo : vlo;
        acc += shi ? -vhi : vhi;
    }
    #pragma unroll
    for (int off = 32; off > 0; off >>= 1) acc += __shfl_down(acc, off, 64);
    __syncthreads();   // all waves' perm reads done before ub reuse
    float* f = (float*)ub;
    if ((tid & 63) == 0) f[tid >> 6] = acc;
    __syncthreads();
    if (tid == 0) {
        float s = 0.f;
        #pragma unroll
        for (int w = 0; w < NT/64; ++w) s += f[w];
        out[b] = s;
    }
}

extern "C" void kernel_launch(void* const* d_in, const int* in_sizes, int n_in,
                              void* d_out, int out_size, void* d_ws, size_t ws_size,
                              hipStream_t stream) {
    const float* x = (const float*)d_in[0];   // (1024, 14) float32
    const float* w = (const float*)d_in[1];   // (6, 14, 3) float32
    float* out = (float*)d_out;               // (1024,) float32
    float* gm = (float*)d_ws;                 // 84*8 floats of Rot matrices

    prep_kernel<<<1, 128, 0, stream>>>(w, gm);
    qsim_kernel<<<BATCH, NT, 0, stream>>>(x, gm, out);
}